// Round 1
// 129.023 us; speedup vs baseline: 1.7958x; 1.7958x over previous
//
#include <hip/hip_runtime.h>

// Problem constants (from reference setup_inputs): N=8, C=19, H=512, W=1024.
#define HWSZ (512 * 1024)        // 524288 = 2^19 pixels per image plane
#define NCLS 19
#define NPIX (8 * HWSZ)          // 4194304 total pixels
#define LOG2_HW 19

// 4 pixels per thread via float4: 16 B/lane loads, all 38 loads batched into
// registers before the compute so ~38 KiB/wave stays in flight (latency fix).
// __launch_bounds__(256, 2): allow up to 256 VGPRs so the allocator keeps the
// 152-float working set live instead of sinking loads into the use chain.
__global__ __launch_bounds__(256, 2) void focal_main(
    const float* __restrict__ lb_g,   // logits_before [N,C,H,W]
    const float* __restrict__ la_g,   // logits_after  [N,C,H,W]
    double* __restrict__ gsum)        // single-slot accumulator in d_ws
{
    const int t  = blockIdx.x * 256 + threadIdx.x;   // quad index in [0, NPIX/4)
    const int p0 = t << 2;                           // first pixel of the quad
    const int n  = p0 >> LOG2_HW;
    const int hw = p0 & (HWSZ - 1);                  // multiple of 4 -> 16B aligned
    const long base = (long)n * NCLS * HWSZ + hw;
    const float4* __restrict__ pb = (const float4*)(lb_g + base);
    const float4* __restrict__ pa = (const float4*)(la_g + base);

    // Load all 2*19 class quads into registers (statically indexed only).
    float lb[NCLS * 4], la[NCLS * 4];
#pragma unroll
    for (int c = 0; c < NCLS; ++c) {
        const float4 v = pb[(long)c * (HWSZ / 4)];
        lb[4 * c + 0] = v.x; lb[4 * c + 1] = v.y;
        lb[4 * c + 2] = v.z; lb[4 * c + 3] = v.w;
    }
#pragma unroll
    for (int c = 0; c < NCLS; ++c) {
        const float4 v = pa[(long)c * (HWSZ / 4)];
        la[4 * c + 0] = v.x; la[4 * c + 1] = v.y;
        la[4 * c + 2] = v.z; la[4 * c + 3] = v.w;
    }

    float tsum = 0.f;
#pragma unroll
    for (int j = 0; j < 4; ++j) {
        // Teacher max + logit_after at the teacher-argmax class (first-max tiebreak).
        float mb = lb[j];
        float la_at_amax = la[j];
#pragma unroll
        for (int c = 1; c < NCLS; ++c) {
            if (lb[4 * c + j] > mb) { mb = lb[4 * c + j]; la_at_amax = la[4 * c + j]; }
        }
        float ma = la[j];
#pragma unroll
        for (int c = 1; c < NCLS; ++c) ma = fmaxf(ma, la[4 * c + j]);

        // One pass: softmax denominators + weighted shifted-logit sums.
        float sum_eb = 0.f, sum_ea = 0.f, dot_a = 0.f, dot_b = 0.f;
#pragma unroll
        for (int c = 0; c < NCLS; ++c) {
            const float sb = lb[4 * c + j] - mb;
            const float sa = la[4 * c + j] - ma;
            const float eb = __expf(sb);
            sum_eb += eb;
            sum_ea += __expf(sa);
            dot_a  += eb * sa;   // Σ eb * (la - ma)
            dot_b  += eb * sb;   // Σ eb * (lb - mb)
        }

        const float inv_sb = 1.0f / sum_eb;
        const float lse_a  = __logf(sum_ea);
        const float lse_b  = __logf(sum_eb);

        // Σ_c pb[c] * log_pa[c]  =  dot_a/sum_eb - lse_a   (<= 0)
        const float ce  = dot_a * inv_sb - lse_a;
        // teacher entropy = lse_b - dot_b/sum_eb           (>= 0)
        const float ent = lse_b - dot_b * inv_sb;

        // focal = | pb[amax] - pa[amax] | ;  pb[amax] = 1/sum_eb
        const float pb_am = inv_sb;
        const float pa_am = __expf(la_at_amax - ma) / sum_ea;
        const float focal = fabsf(pb_am - pa_am);

        float loss = -focal * ce * __expf(-ent);
        tsum += fmaxf(loss, 1e-8f);
    }

    // Wave reduce (64 lanes) -> LDS across 4 waves -> one double atomic per block.
#pragma unroll
    for (int off = 32; off > 0; off >>= 1)
        tsum += __shfl_down(tsum, off);

    __shared__ float wsum[4];
    const int lane = threadIdx.x & 63;
    const int wid  = threadIdx.x >> 6;
    if (lane == 0) wsum[wid] = tsum;
    __syncthreads();
    if (threadIdx.x == 0) {
        const float s = wsum[0] + wsum[1] + wsum[2] + wsum[3];
        atomicAdd(gsum, (double)s);
    }
}

__global__ void focal_final(const double* __restrict__ gsum,
                            float* __restrict__ out)
{
    out[0] = (float)(gsum[0] / (double)NPIX);
}

extern "C" void kernel_launch(void* const* d_in, const int* in_sizes, int n_in,
                              void* d_out, int out_size, void* d_ws, size_t ws_size,
                              hipStream_t stream) {
    const float* lb = (const float*)d_in[0];   // logits_before
    const float* la = (const float*)d_in[1];   // logits_after
    double* gsum = (double*)d_ws;

    hipMemsetAsync(d_ws, 0, sizeof(double), stream);
    focal_main<<<(NPIX / 4) / 256, 256, 0, stream>>>(lb, la, gsum);
    focal_final<<<1, 1, 0, stream>>>(gsum, (float*)d_out);
}